// Round 1
// baseline (180.213 us; speedup 1.0000x reference)
//
#include <hip/hip_runtime.h>

#define M_ROWS 8192
#define K_DIM  4096
#define R_DIM  16
#define N_DIM  4096

__device__ __forceinline__ void fma4(float4& acc, const float4 a, const float4 b) {
    acc.x = fmaf(a.x, b.x, acc.x);
    acc.y = fmaf(a.y, b.y, acc.y);
    acc.z = fmaf(a.z, b.z, acc.z);
    acc.w = fmaf(a.w, b.w, acc.w);
}

__device__ __forceinline__ float hsum4(const float4 v) {
    return (v.x + v.y) + (v.z + v.w);
}

// Kernel 1: t[M][16] = x[M][K] @ A[16][K]^T
// Block: 256 threads, handles 16 rows. Wave kh = tid>>6 owns K-quarter.
// Lane: rg = (lane>>3) -> row pair, sg = (lane&7) -> r pair.
__global__ __launch_bounds__(256) void lora_xat(const float* __restrict__ x,
                                                const float* __restrict__ A,
                                                float* __restrict__ t) {
    const int tid  = threadIdx.x;
    const int kh   = tid >> 6;       // k-quarter 0..3 (one per wave)
    const int lane = tid & 63;
    const int rg   = lane >> 3;      // 0..7 -> rows {2rg, 2rg+1}
    const int sg   = lane & 7;       // 0..7 -> r {2sg, 2sg+1}
    const int rowbase = blockIdx.x * 16;
    const int row0 = rowbase + rg * 2;
    const int r0   = sg * 2;

    const float4* x0 = (const float4*)(x + (size_t)row0 * K_DIM);
    const float4* x1 = (const float4*)(x + (size_t)(row0 + 1) * K_DIM);
    const float4* a0 = (const float4*)(A + (size_t)r0 * K_DIM);
    const float4* a1 = (const float4*)(A + (size_t)(r0 + 1) * K_DIM);

    // K quarter in float4 units: 4096/4/4 = 256 float4 per quarter
    const int kf0 = kh * 256;

    float4 acc00 = {0.f,0.f,0.f,0.f};
    float4 acc01 = {0.f,0.f,0.f,0.f};
    float4 acc10 = {0.f,0.f,0.f,0.f};
    float4 acc11 = {0.f,0.f,0.f,0.f};

    #pragma unroll 4
    for (int i = 0; i < 256; ++i) {
        const int k = kf0 + i;
        float4 xa = x0[k];
        float4 xb = x1[k];
        float4 aa = a0[k];
        float4 ab = a1[k];
        fma4(acc00, xa, aa);
        fma4(acc01, xa, ab);
        fma4(acc10, xb, aa);
        fma4(acc11, xb, ab);
    }

    float s00 = hsum4(acc00);
    float s01 = hsum4(acc01);
    float s10 = hsum4(acc10);
    float s11 = hsum4(acc11);

    // cross-wave (k-quarter) reduction
    __shared__ float red[4][64][5];   // padded to 5 to spread banks
    red[kh][lane][0] = s00;
    red[kh][lane][1] = s01;
    red[kh][lane][2] = s10;
    red[kh][lane][3] = s11;
    __syncthreads();

    if (kh == 0) {
        #pragma unroll
        for (int h = 1; h < 4; ++h) {
            s00 += red[h][lane][0];
            s01 += red[h][lane][1];
            s10 += red[h][lane][2];
            s11 += red[h][lane][3];
        }
        t[(size_t)row0 * R_DIM + r0]           = s00;
        t[(size_t)row0 * R_DIM + r0 + 1]       = s01;
        t[(size_t)(row0 + 1) * R_DIM + r0]     = s10;
        t[(size_t)(row0 + 1) * R_DIM + r0 + 1] = s11;
    }
}

// Kernel 2: out[M][N] = t[M][16] @ B[N][16]^T
// Block: 256 threads, tile = 16 rows x 1024 cols. Thread owns 4 consecutive
// output cols; B rows for those cols live in registers across all 16 rows.
__global__ __launch_bounds__(256) void lora_tb(const float* __restrict__ t,
                                               const float* __restrict__ B,
                                               float* __restrict__ out) {
    const int tid = threadIdx.x;
    const int rb  = blockIdx.x >> 2;      // row tile (16 rows)
    const int ob  = blockIdx.x & 3;       // col chunk (1024 cols)

    __shared__ float4 t_lds[64];          // 16 rows x 16 r
    if (tid < 64) t_lds[tid] = ((const float4*)t)[(size_t)rb * 64 + tid];

    const int o0 = ob * 1024 + tid * 4;   // first of 4 output cols

    float4 breg[4][4];                    // B[o0+j][0..15]
    const float4* B4 = (const float4*)B;
    #pragma unroll
    for (int j = 0; j < 4; ++j) {
        #pragma unroll
        for (int q = 0; q < 4; ++q) {
            breg[j][q] = B4[(size_t)(o0 + j) * 4 + q];
        }
    }
    __syncthreads();

    const size_t rowbase = (size_t)rb * 16;
    float4* out4 = (float4*)out;
    const int ocol4 = ob * 256 + tid;     // float4 index within a row

    #pragma unroll
    for (int row = 0; row < 16; ++row) {
        float a0 = 0.f, a1 = 0.f, a2 = 0.f, a3 = 0.f;
        #pragma unroll
        for (int q = 0; q < 4; ++q) {
            const float4 tq = t_lds[row * 4 + q];
            a0 = fmaf(breg[0][q].x, tq.x, a0);
            a0 = fmaf(breg[0][q].y, tq.y, a0);
            a0 = fmaf(breg[0][q].z, tq.z, a0);
            a0 = fmaf(breg[0][q].w, tq.w, a0);
            a1 = fmaf(breg[1][q].x, tq.x, a1);
            a1 = fmaf(breg[1][q].y, tq.y, a1);
            a1 = fmaf(breg[1][q].z, tq.z, a1);
            a1 = fmaf(breg[1][q].w, tq.w, a1);
            a2 = fmaf(breg[2][q].x, tq.x, a2);
            a2 = fmaf(breg[2][q].y, tq.y, a2);
            a2 = fmaf(breg[2][q].z, tq.z, a2);
            a2 = fmaf(breg[2][q].w, tq.w, a2);
            a3 = fmaf(breg[3][q].x, tq.x, a3);
            a3 = fmaf(breg[3][q].y, tq.y, a3);
            a3 = fmaf(breg[3][q].z, tq.z, a3);
            a3 = fmaf(breg[3][q].w, tq.w, a3);
        }
        float4 o = {a0, a1, a2, a3};
        out4[(rowbase + row) * (N_DIM / 4) + ocol4] = o;
    }
}

extern "C" void kernel_launch(void* const* d_in, const int* in_sizes, int n_in,
                              void* d_out, int out_size, void* d_ws, size_t ws_size,
                              hipStream_t stream) {
    const float* x = (const float*)d_in[0];            // [4,2048,4096]
    const float* B = (const float*)d_in[1];            // [4096,16]
    const float* A = (const float*)d_in[2];            // [16,4096]
    float* out = (float*)d_out;                        // [4,2048,4096]
    float* t   = (float*)d_ws;                         // [8192,16] scratch

    lora_xat<<<M_ROWS / 16, 256, 0, stream>>>(x, A, t);
    lora_tb<<<(M_ROWS / 16) * 4, 256, 0, stream>>>(t, B, out);
}